// Round 2
// baseline (213.449 us; speedup 1.0000x reference)
//
#include <hip/hip_runtime.h>

#define B_  32
#define H_  512
#define W_  512
#define HW_ (H_ * W_)

__device__ __forceinline__ float rcp_fast(float x) { return __builtin_amdgcn_rcpf(x); }

// u_minus = [t1^2 * (1.5 vm - 0.5 vmm) + 2 t0^2 * 0.5 (vm + vp)] / (t1^2 + 2 t0^2)
// (weights 1/3, 2/3 multiplied through; single rcp)
__device__ __forceinline__ float weno_minus(float vmm, float vm, float vp) {
    float d0 = vmm - vm, d1 = vm - vp;
    float t0 = 1e-6f + d0 * d0;
    float t1 = 1e-6f + d1 * d1;
    float s0 = t0 * t0;
    float s1 = t1 * t1;
    float s0x2 = s0 + s0;
    float p0 = 1.5f * vm - 0.5f * vmm;
    float p1 = 0.5f * (vm + vp);
    float num = s1 * p0 + s0x2 * p1;
    return num * rcp_fast(s1 + s0x2);
}

__device__ __forceinline__ float weno_plus(float vmm, float vm, float vp) {
    float d0 = vp - vm, d1 = vm - vmm;
    float t0 = 1e-6f + d0 * d0;
    float t1 = 1e-6f + d1 * d1;
    float s0 = t0 * t0;
    float s1 = t1 * t1;
    float s0x2 = s0 + s0;
    float p0 = 1.5f * vm - 0.5f * vp;
    float p1 = 0.5f * (vm + vmm);
    float num = s1 * p0 + s0x2 * p1;
    return num * rcp_fast(s1 + s0x2);
}

__global__ __launch_bounds__(256) void eikonal_main(
        const float* __restrict__ pred, const float* __restrict__ reach,
        double* __restrict__ acc) {
    const float target = 1.0f / sqrtf((float)(511 * 511 + 511 * 511));
    const float lo = 0.3f * target;
    const float hi = 5.0f * target;

    // group id: 4 pixels along x per thread
    int g = blockIdx.x * 256 + threadIdx.x;      // [0, 2^21)
    int xg = (g & 127) << 2;                     // x0, multiple of 4
    int y  = (g >> 7) & (H_ - 1);
    int b  = g >> 16;

    const float* base = pred + b * HW_;
    const float* rowc = base + y * W_;

    int ym2 = y - 2 < 0 ? 0 : y - 2;
    int ym1 = y - 1 < 0 ? 0 : y - 1;
    int yp1 = y + 1 > H_ - 1 ? H_ - 1 : y + 1;
    int yp2 = y + 2 > H_ - 1 ? H_ - 1 : y + 2;

    int q = xg >> 2;
    float4 c4   = ((const float4*)rowc)[q];
    float4 m2_4 = ((const float4*)(base + ym2 * W_))[q];
    float4 m1_4 = ((const float4*)(base + ym1 * W_))[q];
    float4 p1_4 = ((const float4*)(base + yp1 * W_))[q];
    float4 p2_4 = ((const float4*)(base + yp2 * W_))[q];
    float4 rh4  = ((const float4*)(reach + b * HW_ + y * W_))[q];

    // x-window: pixels xg..xg+3 need clamp(xg-2)..clamp(xg+5)
    int xl2 = xg - 2 < 0 ? 0 : xg - 2;
    int xl1 = xg - 1 < 0 ? 0 : xg - 1;
    int xr1 = xg + 4 > W_ - 1 ? W_ - 1 : xg + 4;
    int xr2 = xg + 5 > W_ - 1 ? W_ - 1 : xg + 5;

    float xs[8];
    xs[0] = rowc[xl2];
    xs[1] = rowc[xl1];
    xs[2] = c4.x; xs[3] = c4.y; xs[4] = c4.z; xs[5] = c4.w;
    xs[6] = rowc[xr1];
    xs[7] = rowc[xr2];

    float fm2[4] = { m2_4.x, m2_4.y, m2_4.z, m2_4.w };
    float fm1[4] = { m1_4.x, m1_4.y, m1_4.z, m1_4.w };
    float fp1[4] = { p1_4.x, p1_4.y, p1_4.z, p1_4.w };
    float fp2[4] = { p2_4.x, p2_4.y, p2_4.z, p2_4.w };
    float rh[4]  = { rh4.x, rh4.y, rh4.z, rh4.w };

    float num = 0.0f;
    float den = 0.0f;

    #pragma unroll
    for (int i = 0; i < 4; ++i) {
        float fxm2 = xs[i];
        float fxm1 = xs[i + 1];
        float f0   = xs[i + 2];
        float fxp1 = xs[i + 3];
        float fxp2 = xs[i + 4];

        float vx_mm = fxm1 - fxm2;
        float vx_m  = f0   - fxm1;
        float vx_c  = fxp1 - f0;
        float vx_p  = fxp2 - fxp1;

        float ux_minus = weno_minus(vx_mm, vx_m, vx_c);
        float ux_plus  = weno_plus(vx_m, vx_c, vx_p);
        float gx = fmaxf(fmaxf(ux_minus, -ux_plus), 0.0f);

        float vy_mm = fm1[i] - fm2[i];
        float vy_m  = f0     - fm1[i];
        float vy_c  = fp1[i] - f0;
        float vy_p  = fp2[i] - fp1[i];

        float uy_minus = weno_minus(vy_mm, vy_m, vy_c);
        float uy_plus  = weno_plus(vy_m, vy_c, vy_p);
        float gy = fmaxf(fmaxf(uy_minus, -uy_plus), 0.0f);

        float gmag = __builtin_amdgcn_sqrtf(gx * gx + gy * gy + 1e-8f);

        float residual = gmag - target;
        float ar = fabsf(residual);
        float per_pixel = (ar < 0.01f) ? (50.0f * residual * residual)
                                       : (ar - 0.005f);

        bool m = (rh[i] > 0.5f) && (gmag >= lo) && (gmag <= hi);
        float sel = m ? 1.0f : 0.0f;
        num = fmaf(sel, per_pixel, num);
        den += sel;
    }

    // wave reduce in double
    double dn = (double)num;
    double dd = (double)den;
    #pragma unroll
    for (int off = 32; off > 0; off >>= 1) {
        dn += __shfl_down(dn, off);
        dd += __shfl_down(dd, off);
    }

    __shared__ double sn[4], sd[4];
    int wid = threadIdx.x >> 6;
    int lane = threadIdx.x & 63;
    if (lane == 0) { sn[wid] = dn; sd[wid] = dd; }
    __syncthreads();
    if (threadIdx.x == 0) {
        double tn = sn[0] + sn[1] + sn[2] + sn[3];
        double td = sd[0] + sd[1] + sd[2] + sd[3];
        atomicAdd(&acc[0], tn);
        atomicAdd(&acc[1], td);
    }
}

__global__ void eikonal_finalize(const double* __restrict__ acc,
                                 float* __restrict__ out) {
    double den = acc[1];
    if (den < 1e-8) den = 1e-8;
    out[0] = (float)(acc[0] / den);
}

extern "C" void kernel_launch(void* const* d_in, const int* in_sizes, int n_in,
                              void* d_out, int out_size, void* d_ws, size_t ws_size,
                              hipStream_t stream) {
    const float* pred  = (const float*)d_in[0];
    const float* reach = (const float*)d_in[1];
    float* out = (float*)d_out;
    double* acc = (double*)d_ws;

    hipMemsetAsync(d_ws, 0, 2 * sizeof(double), stream);

    const int block = 256;
    const int grid = (B_ * H_ * W_) / (4 * block);  // 8192 blocks, 4 px/thread
    eikonal_main<<<grid, block, 0, stream>>>(pred, reach, acc);
    eikonal_finalize<<<1, 1, 0, stream>>>(acc, out);
}

// Round 3
// 212.731 us; speedup vs baseline: 1.0034x; 1.0034x over previous
//
#include <hip/hip_runtime.h>

#define B_  32
#define H_  512
#define W_  512
#define HW_ (H_ * W_)

__device__ __forceinline__ float rcp_fast(float x) { return __builtin_amdgcn_rcpf(x); }

// WENO3: single fast-rcp form.  u_minus = (s1*p0 + 2*s0*p1) / (s1 + 2*s0)
__device__ __forceinline__ float weno_minus(float vmm, float vm, float vp) {
    float d0 = vmm - vm, d1 = vm - vp;
    float t0 = 1e-6f + d0 * d0;
    float t1 = 1e-6f + d1 * d1;
    float s0 = t0 * t0, s1 = t1 * t1;
    float s0x2 = s0 + s0;
    float p0 = 1.5f * vm - 0.5f * vmm;
    float p1 = 0.5f * (vm + vp);
    return (s1 * p0 + s0x2 * p1) * rcp_fast(s1 + s0x2);
}

__device__ __forceinline__ float weno_plus(float vmm, float vm, float vp) {
    float d0 = vp - vm, d1 = vm - vmm;
    float t0 = 1e-6f + d0 * d0;
    float t1 = 1e-6f + d1 * d1;
    float s0 = t0 * t0, s1 = t1 * t1;
    float s0x2 = s0 + s0;
    float p0 = 1.5f * vm - 0.5f * vp;
    float p1 = 0.5f * (vm + vmm);
    return (s1 * p0 + s0x2 * p1) * rcp_fast(s1 + s0x2);
}

// One pixel: all operands are named scalars -> stays in VGPRs.
__device__ __forceinline__ void pixel_eval(
        float vxmm, float vxm, float vxc, float vxp,
        float vymm, float vym, float vyc, float vyp,
        float rh, float target, float lo, float hi,
        float& num, float& den) {
    float ux_minus = weno_minus(vxmm, vxm, vxc);
    float ux_plus  = weno_plus(vxm, vxc, vxp);
    float gx = fmaxf(fmaxf(ux_minus, -ux_plus), 0.0f);

    float uy_minus = weno_minus(vymm, vym, vyc);
    float uy_plus  = weno_plus(vym, vyc, vyp);
    float gy = fmaxf(fmaxf(uy_minus, -uy_plus), 0.0f);

    float gmag = __builtin_amdgcn_sqrtf(gx * gx + gy * gy + 1e-8f);

    float residual = gmag - target;
    float ar = fabsf(residual);
    float per_pixel = (ar < 0.01f) ? (50.0f * residual * residual)
                                   : (ar - 0.005f);

    bool m = (rh > 0.5f) && (gmag >= lo) && (gmag <= hi);
    float sel = m ? 1.0f : 0.0f;
    num = fmaf(sel, per_pixel, num);
    den += sel;
}

__global__ __launch_bounds__(256) void eikonal_main(
        const float* __restrict__ pred, const float* __restrict__ reach,
        double* __restrict__ acc) {
    const float target = 1.0f / sqrtf((float)(511 * 511 + 511 * 511));
    const float lo = 0.3f * target;
    const float hi = 5.0f * target;

    int g = blockIdx.x * 256 + threadIdx.x;      // [0, 2^21)
    int xg = (g & 127) << 2;                     // x0, multiple of 4
    int y  = (g >> 7) & (H_ - 1);
    int b  = g >> 16;

    const float* base = pred + b * HW_;
    const float* rowc = base + y * W_;

    int ym2 = y - 2 < 0 ? 0 : y - 2;
    int ym1 = y - 1 < 0 ? 0 : y - 1;
    int yp1 = y + 1 > H_ - 1 ? H_ - 1 : y + 1;
    int yp2 = y + 2 > H_ - 1 ? H_ - 1 : y + 2;

    int q = xg >> 2;
    // Issue all global loads up front (independent -> MLP).
    float4 c4   = ((const float4*)rowc)[q];
    float4 m2v  = ((const float4*)(base + ym2 * W_))[q];
    float4 m1v  = ((const float4*)(base + ym1 * W_))[q];
    float4 p1v  = ((const float4*)(base + yp1 * W_))[q];
    float4 p2v  = ((const float4*)(base + yp2 * W_))[q];
    float4 rh4  = ((const float4*)(reach + b * HW_ + y * W_))[q];

    int xl2 = xg - 2 < 0 ? 0 : xg - 2;
    int xl1 = xg - 1 < 0 ? 0 : xg - 1;
    int xr1 = xg + 4 > W_ - 1 ? W_ - 1 : xg + 4;
    int xr2 = xg + 5 > W_ - 1 ? W_ - 1 : xg + 5;
    float eL2 = rowc[xl2];
    float eL1 = rowc[xl1];
    float eR1 = rowc[xr1];
    float eR2 = rowc[xr2];

    // 7 shared x-direction forward differences for pixels xg..xg+3
    float dx0 = eL1  - eL2;
    float dx1 = c4.x - eL1;
    float dx2 = c4.y - c4.x;
    float dx3 = c4.z - c4.y;
    float dx4 = c4.w - c4.z;
    float dx5 = eR1  - c4.w;
    float dx6 = eR2  - eR1;

    float num = 0.0f, den = 0.0f;

    pixel_eval(dx0, dx1, dx2, dx3,
               m1v.x - m2v.x, c4.x - m1v.x, p1v.x - c4.x, p2v.x - p1v.x,
               rh4.x, target, lo, hi, num, den);
    pixel_eval(dx1, dx2, dx3, dx4,
               m1v.y - m2v.y, c4.y - m1v.y, p1v.y - c4.y, p2v.y - p1v.y,
               rh4.y, target, lo, hi, num, den);
    pixel_eval(dx2, dx3, dx4, dx5,
               m1v.z - m2v.z, c4.z - m1v.z, p1v.z - c4.z, p2v.z - p1v.z,
               rh4.z, target, lo, hi, num, den);
    pixel_eval(dx3, dx4, dx5, dx6,
               m1v.w - m2v.w, c4.w - m1v.w, p1v.w - c4.w, p2v.w - p1v.w,
               rh4.w, target, lo, hi, num, den);

    // wave reduce in double
    double dn = (double)num;
    double dd = (double)den;
    #pragma unroll
    for (int off = 32; off > 0; off >>= 1) {
        dn += __shfl_down(dn, off);
        dd += __shfl_down(dd, off);
    }

    __shared__ double sn[4], sd[4];
    int wid = threadIdx.x >> 6;
    int lane = threadIdx.x & 63;
    if (lane == 0) { sn[wid] = dn; sd[wid] = dd; }
    __syncthreads();
    if (threadIdx.x == 0) {
        double tn = sn[0] + sn[1] + sn[2] + sn[3];
        double td = sd[0] + sd[1] + sd[2] + sd[3];
        atomicAdd(&acc[0], tn);
        atomicAdd(&acc[1], td);
    }
}

__global__ void eikonal_finalize(const double* __restrict__ acc,
                                 float* __restrict__ out) {
    double den = acc[1];
    if (den < 1e-8) den = 1e-8;
    out[0] = (float)(acc[0] / den);
}

extern "C" void kernel_launch(void* const* d_in, const int* in_sizes, int n_in,
                              void* d_out, int out_size, void* d_ws, size_t ws_size,
                              hipStream_t stream) {
    const float* pred  = (const float*)d_in[0];
    const float* reach = (const float*)d_in[1];
    float* out = (float*)d_out;
    double* acc = (double*)d_ws;

    hipMemsetAsync(d_ws, 0, 2 * sizeof(double), stream);

    const int block = 256;
    const int grid = (B_ * H_ * W_) / (4 * block);  // 8192 blocks, 4 px/thread
    eikonal_main<<<grid, block, 0, stream>>>(pred, reach, acc);
    eikonal_finalize<<<1, 1, 0, stream>>>(acc, out);
}

// Round 4
// 34.523 us; speedup vs baseline: 6.1829x; 6.1621x over previous
//
#include <hip/hip_runtime.h>

#define B_  32
#define H_  512
#define W_  512
#define HW_ (H_ * W_)
#define TH_ 8                  // pixel rows per block
#define NROWS_ (TH_ + 4)       // staged rows incl. +-2 halo
#define PITCH_ 520             // LDS row pitch in floats: [2 spare][2 halo][512 core][2 halo][2 spare]; core at col 4
#define CORE_ 4
#define NBLK_ (B_ * H_ / TH_)  // 2048 blocks

__device__ __forceinline__ float rcp_fast(float x) { return __builtin_amdgcn_rcpf(x); }

// WENO3, single fast-rcp form
__device__ __forceinline__ float weno_minus(float vmm, float vm, float vp) {
    float d0 = vmm - vm, d1 = vm - vp;
    float t0 = 1e-6f + d0 * d0;
    float t1 = 1e-6f + d1 * d1;
    float s0 = t0 * t0, s1 = t1 * t1;
    float s0x2 = s0 + s0;
    float p0 = 1.5f * vm - 0.5f * vmm;
    float p1 = 0.5f * (vm + vp);
    return (s1 * p0 + s0x2 * p1) * rcp_fast(s1 + s0x2);
}

__device__ __forceinline__ float weno_plus(float vmm, float vm, float vp) {
    float d0 = vp - vm, d1 = vm - vmm;
    float t0 = 1e-6f + d0 * d0;
    float t1 = 1e-6f + d1 * d1;
    float s0 = t0 * t0, s1 = t1 * t1;
    float s0x2 = s0 + s0;
    float p0 = 1.5f * vm - 0.5f * vp;
    float p1 = 0.5f * (vm + vmm);
    return (s1 * p0 + s0x2 * p1) * rcp_fast(s1 + s0x2);
}

__device__ __forceinline__ void pixel_eval(
        float vxmm, float vxm, float vxc, float vxp,
        float vymm, float vym, float vyc, float vyp,
        float rh, float target, float lo, float hi,
        float& num, float& den) {
    float ux_minus = weno_minus(vxmm, vxm, vxc);
    float ux_plus  = weno_plus(vxm, vxc, vxp);
    float gx = fmaxf(fmaxf(ux_minus, -ux_plus), 0.0f);

    float uy_minus = weno_minus(vymm, vym, vyc);
    float uy_plus  = weno_plus(vym, vyc, vyp);
    float gy = fmaxf(fmaxf(uy_minus, -uy_plus), 0.0f);

    float gmag = __builtin_amdgcn_sqrtf(gx * gx + gy * gy + 1e-8f);

    float residual = gmag - target;
    float ar = fabsf(residual);
    float per_pixel = (ar < 0.01f) ? (50.0f * residual * residual)
                                   : (ar - 0.005f);

    bool m = (rh > 0.5f) && (gmag >= lo) && (gmag <= hi);
    float sel = m ? 1.0f : 0.0f;
    num = fmaf(sel, per_pixel, num);
    den += sel;
}

__global__ __launch_bounds__(256) void eikonal_main(
        const float* __restrict__ pred, const float* __restrict__ reach,
        double2* __restrict__ partials) {
    const float target = 1.0f / sqrtf((float)(511 * 511 + 511 * 511));
    const float lo = 0.3f * target;
    const float hi = 5.0f * target;

    __shared__ float tile[NROWS_ * PITCH_];   // 12 x 520 floats = 24.96 KB

    int bb = blockIdx.x;
    int b  = bb >> 6;            // 64 blocks per image (512/8)
    int y0 = (bb & 63) * TH_;
    const float* base = pred + b * HW_;
    int t = threadIdx.x;

    // ---- stage 12 rows x 512 floats: 1536 float4, 6 per thread ----
    #pragma unroll
    for (int k = 0; k < 6; ++k) {
        int v  = t + (k << 8);       // 0..1535
        int r  = v >> 7;             // staged row 0..11
        int c4 = v & 127;            // float4 col
        int cy = y0 - 2 + r;
        cy = cy < 0 ? 0 : (cy > H_ - 1 ? H_ - 1 : cy);
        float4 d = *(const float4*)(base + (cy << 9) + (c4 << 2));
        *(float4*)(&tile[r * PITCH_ + CORE_ + (c4 << 2)]) = d;   // 16B-aligned
    }
    // ---- x halo columns (edge clamp): cols 2,3 <- x=0 ; cols 516,517 <- x=511 ----
    if (t < NROWS_) {
        int cy = y0 - 2 + t;
        cy = cy < 0 ? 0 : (cy > H_ - 1 ? H_ - 1 : cy);
        float v = base[(cy << 9)];
        tile[t * PITCH_ + 2] = v;
        tile[t * PITCH_ + 3] = v;
    } else if (t >= 32 && t < 32 + NROWS_) {
        int r = t - 32;
        int cy = y0 - 2 + r;
        cy = cy < 0 ? 0 : (cy > H_ - 1 ? H_ - 1 : cy);
        float v = base[(cy << 9) + (W_ - 1)];
        tile[r * PITCH_ + CORE_ + W_] = v;
        tile[r * PITCH_ + CORE_ + W_ + 1] = v;
    }
    __syncthreads();

    // ---- compute: thread t -> pixel row rr = t>>5, cols (t&31)*4 + 128*j ----
    int rr = t >> 5;                 // 0..7
    int cx = (t & 31) << 2;          // 0..124
    const float* rrow = reach + b * HW_ + ((y0 + rr) << 9);

    float num = 0.0f, den = 0.0f;

    #pragma unroll
    for (int j = 0; j < 4; ++j) {
        int c0 = cx + (j << 7);      // pixel x of first of 4
        int cen = (rr + 2) * PITCH_ + CORE_ + c0;

        // x window: pixels c0..c0+3 need x = c0-2 .. c0+5 -> padded cols cen-2 .. cen+5
        float2 xl = *(const float2*)(&tile[cen - 2]);   // 8B-aligned
        float4 xc = *(const float4*)(&tile[cen]);       // 16B-aligned
        float2 xr = *(const float2*)(&tile[cen + 4]);   // 16B-aligned

        float4 ym2 = *(const float4*)(&tile[(rr + 0) * PITCH_ + CORE_ + c0]);
        float4 ym1 = *(const float4*)(&tile[(rr + 1) * PITCH_ + CORE_ + c0]);
        float4 yp1 = *(const float4*)(&tile[(rr + 3) * PITCH_ + CORE_ + c0]);
        float4 yp2 = *(const float4*)(&tile[(rr + 4) * PITCH_ + CORE_ + c0]);

        float4 rh4 = *(const float4*)(rrow + c0);

        // 7 shared x forward differences
        float dx0 = xl.y - xl.x;
        float dx1 = xc.x - xl.y;
        float dx2 = xc.y - xc.x;
        float dx3 = xc.z - xc.y;
        float dx4 = xc.w - xc.z;
        float dx5 = xr.x - xc.w;
        float dx6 = xr.y - xr.x;

        pixel_eval(dx0, dx1, dx2, dx3,
                   ym1.x - ym2.x, xc.x - ym1.x, yp1.x - xc.x, yp2.x - yp1.x,
                   rh4.x, target, lo, hi, num, den);
        pixel_eval(dx1, dx2, dx3, dx4,
                   ym1.y - ym2.y, xc.y - ym1.y, yp1.y - xc.y, yp2.y - yp1.y,
                   rh4.y, target, lo, hi, num, den);
        pixel_eval(dx2, dx3, dx4, dx5,
                   ym1.z - ym2.z, xc.z - ym1.z, yp1.z - xc.z, yp2.z - yp1.z,
                   rh4.z, target, lo, hi, num, den);
        pixel_eval(dx3, dx4, dx5, dx6,
                   ym1.w - ym2.w, xc.w - ym1.w, yp1.w - xc.w, yp2.w - yp1.w,
                   rh4.w, target, lo, hi, num, den);
    }

    // ---- block reduction (no global atomics) ----
    double dn = (double)num;
    double dd = (double)den;
    #pragma unroll
    for (int off = 32; off > 0; off >>= 1) {
        dn += __shfl_down(dn, off);
        dd += __shfl_down(dd, off);
    }
    __shared__ double sn[4], sd[4];
    int wid  = t >> 6;
    int lane = t & 63;
    if (lane == 0) { sn[wid] = dn; sd[wid] = dd; }
    __syncthreads();
    if (t == 0) {
        double2 p;
        p.x = sn[0] + sn[1] + sn[2] + sn[3];
        p.y = sd[0] + sd[1] + sd[2] + sd[3];
        partials[bb] = p;
    }
}

__global__ __launch_bounds__(256) void eikonal_finalize(
        const double2* __restrict__ partials, float* __restrict__ out) {
    int t = threadIdx.x;
    double n = 0.0, d = 0.0;
    #pragma unroll
    for (int k = 0; k < NBLK_ / 256; ++k) {
        double2 p = partials[t + (k << 8)];
        n += p.x;
        d += p.y;
    }
    #pragma unroll
    for (int off = 32; off > 0; off >>= 1) {
        n += __shfl_down(n, off);
        d += __shfl_down(d, off);
    }
    __shared__ double sn[4], sd[4];
    int wid  = t >> 6;
    int lane = t & 63;
    if (lane == 0) { sn[wid] = n; sd[wid] = d; }
    __syncthreads();
    if (t == 0) {
        double num = sn[0] + sn[1] + sn[2] + sn[3];
        double den = sd[0] + sd[1] + sd[2] + sd[3];
        if (den < 1e-8) den = 1e-8;
        out[0] = (float)(num / den);
    }
}

extern "C" void kernel_launch(void* const* d_in, const int* in_sizes, int n_in,
                              void* d_out, int out_size, void* d_ws, size_t ws_size,
                              hipStream_t stream) {
    const float* pred  = (const float*)d_in[0];
    const float* reach = (const float*)d_in[1];
    float* out = (float*)d_out;
    double2* partials = (double2*)d_ws;   // 2048 * 16B = 32 KB, fully written each call

    eikonal_main<<<NBLK_, 256, 0, stream>>>(pred, reach, partials);
    eikonal_finalize<<<1, 256, 0, stream>>>(partials, out);
}

// Round 5
// 34.522 us; speedup vs baseline: 6.1830x; 1.0000x over previous
//
#include <hip/hip_runtime.h>

#define B_  32
#define H_  512
#define W_  512
#define HW_ (H_ * W_)
#define RSTRIP_ 16
#define NBLK_ 512              // 512 blocks * 256 thr = 2048 waves = 32 img * 32 strips * 2 halves

__device__ __forceinline__ float rcp_fast(float x) { return __builtin_amdgcn_rcpf(x); }

// WENO3, single fast-rcp form (validated rounds 1-4, absmax 0.0)
__device__ __forceinline__ float weno_minus(float vmm, float vm, float vp) {
    float d0 = vmm - vm, d1 = vm - vp;
    float t0 = 1e-6f + d0 * d0;
    float t1 = 1e-6f + d1 * d1;
    float s0 = t0 * t0, s1 = t1 * t1;
    float s0x2 = s0 + s0;
    float p0 = 1.5f * vm - 0.5f * vmm;
    float p1 = 0.5f * (vm + vp);
    return (s1 * p0 + s0x2 * p1) * rcp_fast(s1 + s0x2);
}

__device__ __forceinline__ float weno_plus(float vmm, float vm, float vp) {
    float d0 = vp - vm, d1 = vm - vmm;
    float t0 = 1e-6f + d0 * d0;
    float t1 = 1e-6f + d1 * d1;
    float s0 = t0 * t0, s1 = t1 * t1;
    float s0x2 = s0 + s0;
    float p0 = 1.5f * vm - 0.5f * vp;
    float p1 = 0.5f * (vm + vmm);
    return (s1 * p0 + s0x2 * p1) * rcp_fast(s1 + s0x2);
}

__device__ __forceinline__ void pixel_eval(
        float vxmm, float vxm, float vxc, float vxp,
        float vymm, float vym, float vyc, float vyp,
        float rh, float target, float lo, float hi,
        float& num, float& den) {
    float ux_minus = weno_minus(vxmm, vxm, vxc);
    float ux_plus  = weno_plus(vxm, vxc, vxp);
    float gx = fmaxf(fmaxf(ux_minus, -ux_plus), 0.0f);

    float uy_minus = weno_minus(vymm, vym, vyc);
    float uy_plus  = weno_plus(vym, vyc, vyp);
    float gy = fmaxf(fmaxf(uy_minus, -uy_plus), 0.0f);

    float gmag = __builtin_amdgcn_sqrtf(gx * gx + gy * gy + 1e-8f);

    float residual = gmag - target;
    float ar = fabsf(residual);
    float per_pixel = (ar < 0.01f) ? (50.0f * residual * residual)
                                   : (ar - 0.005f);

    bool m = (rh > 0.5f) && (gmag >= lo) && (gmag <= hi);
    float sel = m ? 1.0f : 0.0f;
    num = fmaf(sel, per_pixel, num);
    den += sel;
}

__device__ __forceinline__ int clampy(int v) {
    return v < 0 ? 0 : (v > H_ - 1 ? H_ - 1 : v);
}

__global__ __launch_bounds__(256) void eikonal_main(
        const float* __restrict__ pred, const float* __restrict__ reach,
        double2* __restrict__ partials) {
    const float target = 1.0f / sqrtf((float)(511 * 511 + 511 * 511));
    const float lo = 0.3f * target;
    const float hi = 5.0f * target;

    int t = threadIdx.x;
    int lane = t & 63;
    int wv = blockIdx.x * 4 + (t >> 6);   // 0..2047
    int b  = wv >> 6;                     // image
    int r  = wv & 63;
    int s  = r >> 1;                      // strip 0..31
    int h  = r & 1;                       // row half
    int y0 = s * RSTRIP_;
    int x0 = (h << 8) + (lane << 2);      // 4 consecutive px per lane

    const float* base  = pred  + b * HW_ + x0;
    const float* rbase = reach + b * HW_ + x0;
    const float* hbase = pred  + b * HW_;

    bool lane0  = (lane == 0);
    bool lane63 = (lane == 63);
    bool haloL = lane0  && (h == 1);      // needs x = 254,255
    bool haloR = lane63 && (h == 0);      // needs x = 256,257
    bool needs_halo = haloL || haloR;
    int hx = haloL ? 254 : 256;

    // ---- prologue: 6-deep pred row chain (y0-2 .. y0+3), 4-deep halo, 2-deep reach
    float4 pm2 = *(const float4*)(base + (clampy(y0 - 2) << 9));
    float4 pm1 = *(const float4*)(base + (clampy(y0 - 1) << 9));
    float4 p0c = *(const float4*)(base + ((y0    ) << 9));
    float4 pp1 = *(const float4*)(base + ((y0 + 1) << 9));
    float4 pp2 = *(const float4*)(base + ((y0 + 2) << 9));
    float4 pp3 = *(const float4*)(base + ((y0 + 3) << 9));

    float2 h0c = make_float2(0.f, 0.f), h1c = h0c, h2c = h0c, h3c = h0c;
    if (needs_halo) {
        h0c = *(const float2*)(hbase + ((y0    ) << 9) + hx);
        h1c = *(const float2*)(hbase + ((y0 + 1) << 9) + hx);
        h2c = *(const float2*)(hbase + ((y0 + 2) << 9) + hx);
        h3c = *(const float2*)(hbase + ((y0 + 3) << 9) + hx);
    }
    float4 q0 = *(const float4*)(rbase + ((y0    ) << 9));
    float4 q1 = *(const float4*)(rbase + ((y0 + 1) << 9));

    float num = 0.0f, den = 0.0f;

    #pragma unroll 4
    for (int i = 0; i < RSTRIP_; ++i) {
        int y = y0 + i;
        int yld = clampy(y + 4);
        // prefetch (used 2+ iterations later -> ~1000 cy slack)
        float4 pnew = *(const float4*)(base + (yld << 9));
        float2 hnew = make_float2(0.f, 0.f);
        if (needs_halo) hnew = *(const float2*)(hbase + (yld << 9) + hx);
        int yq = y + 2 > H_ - 1 ? H_ - 1 : y + 2;
        float4 qnew = *(const float4*)(rbase + (yq << 9));

        // x-neighbors of current row via cross-lane shuffle
        float lz = __shfl_up(p0c.z, 1);     // x0-2
        float lw = __shfl_up(p0c.w, 1);     // x0-1
        float rx = __shfl_down(p0c.x, 1);   // x0+4
        float ry = __shfl_down(p0c.y, 1);   // x0+5
        if (lane0)  { lz = (h == 1) ? h0c.x : p0c.x; lw = (h == 1) ? h0c.y : p0c.x; }
        if (lane63) { rx = (h == 0) ? h0c.x : p0c.w; ry = (h == 0) ? h0c.y : p0c.w; }

        // 7 shared x forward differences
        float dx0 = lw    - lz;
        float dx1 = p0c.x - lw;
        float dx2 = p0c.y - p0c.x;
        float dx3 = p0c.z - p0c.y;
        float dx4 = p0c.w - p0c.z;
        float dx5 = rx    - p0c.w;
        float dx6 = ry    - rx;

        pixel_eval(dx0, dx1, dx2, dx3,
                   pm1.x - pm2.x, p0c.x - pm1.x, pp1.x - p0c.x, pp2.x - pp1.x,
                   q0.x, target, lo, hi, num, den);
        pixel_eval(dx1, dx2, dx3, dx4,
                   pm1.y - pm2.y, p0c.y - pm1.y, pp1.y - p0c.y, pp2.y - pp1.y,
                   q0.y, target, lo, hi, num, den);
        pixel_eval(dx2, dx3, dx4, dx5,
                   pm1.z - pm2.z, p0c.z - pm1.z, pp1.z - p0c.z, pp2.z - pp1.z,
                   q0.z, target, lo, hi, num, den);
        pixel_eval(dx3, dx4, dx5, dx6,
                   pm1.w - pm2.w, p0c.w - pm1.w, pp1.w - p0c.w, pp2.w - pp1.w,
                   q0.w, target, lo, hi, num, den);

        // roll chains (register renaming, no copies after unroll)
        pm2 = pm1; pm1 = p0c; p0c = pp1; pp1 = pp2; pp2 = pp3; pp3 = pnew;
        h0c = h1c; h1c = h2c; h2c = h3c; h3c = hnew;
        q0 = q1; q1 = qnew;
    }

    // ---- block reduction ----
    double dn = (double)num;
    double dd = (double)den;
    #pragma unroll
    for (int off = 32; off > 0; off >>= 1) {
        dn += __shfl_down(dn, off);
        dd += __shfl_down(dd, off);
    }
    __shared__ double sn[4], sd[4];
    int wid = t >> 6;
    if (lane == 0) { sn[wid] = dn; sd[wid] = dd; }
    __syncthreads();
    if (t == 0) {
        double2 p;
        p.x = sn[0] + sn[1] + sn[2] + sn[3];
        p.y = sd[0] + sd[1] + sd[2] + sd[3];
        partials[blockIdx.x] = p;
    }
}

__global__ __launch_bounds__(256) void eikonal_finalize(
        const double2* __restrict__ partials, float* __restrict__ out) {
    int t = threadIdx.x;
    double n = 0.0, d = 0.0;
    #pragma unroll
    for (int k = 0; k < NBLK_ / 256; ++k) {
        double2 p = partials[t + (k << 8)];
        n += p.x;
        d += p.y;
    }
    #pragma unroll
    for (int off = 32; off > 0; off >>= 1) {
        n += __shfl_down(n, off);
        d += __shfl_down(d, off);
    }
    __shared__ double sn[4], sd[4];
    int wid = t >> 6;
    int lane = t & 63;
    if (lane == 0) { sn[wid] = n; sd[wid] = d; }
    __syncthreads();
    if (t == 0) {
        double num = sn[0] + sn[1] + sn[2] + sn[3];
        double den = sd[0] + sd[1] + sd[2] + sd[3];
        if (den < 1e-8) den = 1e-8;
        out[0] = (float)(num / den);
    }
}

extern "C" void kernel_launch(void* const* d_in, const int* in_sizes, int n_in,
                              void* d_out, int out_size, void* d_ws, size_t ws_size,
                              hipStream_t stream) {
    const float* pred  = (const float*)d_in[0];
    const float* reach = (const float*)d_in[1];
    float* out = (float*)d_out;
    double2* partials = (double2*)d_ws;   // 512 * 16B = 8 KB, fully rewritten each call

    eikonal_main<<<NBLK_, 256, 0, stream>>>(pred, reach, partials);
    eikonal_finalize<<<1, 256, 0, stream>>>(partials, out);
}